// Round 1
// baseline (44.262 us; speedup 1.0000x reference)
//
#include <hip/hip_runtime.h>
#include <hip/hip_bf16.h>

using frag_ab = __attribute__((ext_vector_type(8))) short;   // 8 bf16 in 4 VGPRs
using f32x4   = __attribute__((ext_vector_type(4))) float;

__device__ __forceinline__ unsigned short f2bf(float f) {
    unsigned u = __float_as_uint(f);
    u += 0x7fffu + ((u >> 16) & 1u);          // RNE
    return (unsigned short)(u >> 16);
}

// One block = 256 threads = 4 waves; each wave handles one (b,c) pair.
// Per pair: C(16x80) = A(16 windows x 320) * B(320 x 80 twiddle), bf16 MFMA.
// B cols 0..34 = cos(2*pi*(7+j)*k/300), cols 35..69 = sin(...), 70..79 = 0.
__global__ __launch_bounds__(256) void st_spec_kernel(
    const float* __restrict__ x, const int* __restrict__ offs,
    float* __restrict__ out)
{
    __shared__ __align__(16) short Bp[25600];   // [kc=10][n=5][lane=64][e=8] bf16 bits, 51200 B
    __shared__ float Cbuf[4][16 * 80];          // per-wave C scratch, 20480 B
    __shared__ float cT[300], sT[300];          // 2400 B

    const int tid = threadIdx.x;

    // phase 0: small exact-angle table  cos/sin(2*pi*m/300)
    for (int m = tid; m < 300; m += 256) {
        float s, c;
        sincosf((float)m * 0.020943951023931953f, &s, &c);
        cT[m] = c; sT[m] = s;
    }
    __syncthreads();

    // phase 1: build twiddle B in MFMA fragment order (lane l: k=(l>>4)*8+e, col=l&15)
    for (int i = tid; i < 25600; i += 256) {
        int e  = i & 7;
        int l  = (i >> 3) & 63;
        int nk = i >> 9;               // kc*5 + n
        int kc = nk / 5;
        int n  = nk - kc * 5;
        int k   = kc * 32 + ((l >> 4) << 3) + e;
        int col = n * 16 + (l & 15);
        float v = 0.0f;
        if (k < 300 && col < 70) {
            int j = (col < 35) ? col : col - 35;
            int m = ((7 + j) * k) % 300;       // exact integer angle index
            v = (col < 35) ? cT[m] : sT[m];
        }
        Bp[i] = (short)f2bf(v);
    }
    __syncthreads();

    // phase 2: per-wave GEMM
    const int wave = tid >> 6;
    const int lane = tid & 63;
    const int bc   = blockIdx.x * 4 + wave;     // 0..4095  (b*32+c)
    const int w16  = lane & 15;                 // A row = window index
    const int kq   = lane >> 4;                 // k-quarter

    const float* xrow = x + (size_t)bc * 9000;
    const int off = offs[bc * 16 + w16];

    // A fragments straight from global (runtime offsets), zero-pad t>=300
    frag_ab a[10];
    #pragma unroll
    for (int kc = 0; kc < 9; ++kc) {           // t <= 287+8 = 295 < 300, safe
        const float* p = xrow + off + kc * 32 + kq * 8;
        frag_ab av;
        #pragma unroll
        for (int e = 0; e < 8; ++e) av[e] = (short)f2bf(p[e]);
        a[kc] = av;
    }
    {
        int tb = 288 + kq * 8;                 // last chunk: guard t<300
        frag_ab av;
        #pragma unroll
        for (int e = 0; e < 8; ++e) {
            int t = tb + e;
            av[e] = (short)f2bf((t < 300) ? xrow[off + t] : 0.0f);
        }
        a[9] = av;
    }

    f32x4 acc[5];
    #pragma unroll
    for (int n = 0; n < 5; ++n) acc[n] = (f32x4){0.f, 0.f, 0.f, 0.f};

    #pragma unroll
    for (int kc = 0; kc < 10; ++kc) {
        #pragma unroll
        for (int n = 0; n < 5; ++n) {
            frag_ab b = *(const frag_ab*)&Bp[((kc * 5 + n) * 64 + lane) * 8];
            acc[n] = __builtin_amdgcn_mfma_f32_16x16x32_bf16(a[kc], b, acc[n], 0, 0, 0);
        }
    }

    // epilogue: C fragment layout col=lane&15 (bin), row=(lane>>4)*4+r (window)
    float* C = Cbuf[wave];
    #pragma unroll
    for (int n = 0; n < 5; ++n)
        #pragma unroll
        for (int r = 0; r < 4; ++r)
            C[(kq * 4 + r) * 80 + n * 16 + w16] = acc[n][r];

    __syncthreads();

    // 4 lanes per window: power + normalize over 35 bins
    const int w   = lane >> 2;
    const int sub = lane & 3;
    float pv[9];
    float s = 0.f;
    #pragma unroll
    for (int i2 = 0; i2 < 9; ++i2) {
        int j = sub * 9 + i2;
        float p = 0.f;
        if (j < 35) {
            float re = C[w * 80 + j];
            float im = C[w * 80 + 35 + j];
            p = re * re + im * im;
        }
        pv[i2] = p;
        s += p;
    }
    s += __shfl_xor(s, 1);
    s += __shfl_xor(s, 2);
    float inv = 1.0f / s;
    float* orow = out + ((size_t)bc * 16 + w) * 35;
    #pragma unroll
    for (int i2 = 0; i2 < 9; ++i2) {
        int j = sub * 9 + i2;
        if (j < 35) orow[j] = pv[i2] * inv;
    }
}

extern "C" void kernel_launch(void* const* d_in, const int* in_sizes, int n_in,
                              void* d_out, int out_size, void* d_ws, size_t ws_size,
                              hipStream_t stream) {
    const float* x    = (const float*)d_in[0];
    const int*   offs = (const int*)d_in[1];
    float*       out  = (float*)d_out;
    // 4096 (b,c) pairs, 4 per block
    hipLaunchKernelGGL(st_spec_kernel, dim3(1024), dim3(256), 0, stream,
                       x, offs, out);
}

// Round 2
// 27.704 us; speedup vs baseline: 1.5977x; 1.5977x over previous
//
#include <hip/hip_runtime.h>
#include <hip/hip_bf16.h>

using frag_ab = __attribute__((ext_vector_type(8))) short;   // 8 bf16 in 4 VGPRs
using f32x4   = __attribute__((ext_vector_type(4))) float;
typedef float f32x4u __attribute__((ext_vector_type(4), aligned(4)));
using u16x8   = __attribute__((ext_vector_type(8))) unsigned short;  // 16 B

__device__ __forceinline__ unsigned short f2bf(float f) {
    unsigned u = __float_as_uint(f);
    u += 0x7fffu + ((u >> 16) & 1u);          // RNE
    return (unsigned short)(u >> 16);
}

// One element of the packed twiddle table Bp[25600]:
// layout [kc=10][n=5][lane=64][e=8], lane l: k=(l>>4)*8+e + kc*32, col=n*16+(l&15)
// col 0..34 = cos(2*pi*(7+j)*k/300), col 35..69 = sin(...), 70..79 = 0
__device__ __forceinline__ unsigned short bp_elem(int i) {
    int e  = i & 7;
    int l  = (i >> 3) & 63;
    int nk = i >> 9;               // kc*5 + n
    int kc = nk / 5;
    int n  = nk - kc * 5;
    int k   = kc * 32 + ((l >> 4) << 3) + e;
    int col = n * 16 + (l & 15);
    float v = 0.0f;
    if (k < 300 && col < 70) {
        int j = (col < 35) ? col : col - 35;
        int m = ((7 + j) * k) % 300;           // exact integer angle index
        float s, c;
        sincosf((float)m * 0.020943951023931953f, &s, &c);
        v = (col < 35) ? c : s;
    }
    return f2bf(v);
}

__global__ __launch_bounds__(256) void build_twiddle(unsigned short* __restrict__ BpG) {
    int i = blockIdx.x * 256 + threadIdx.x;
    if (i < 25600) BpG[i] = bp_elem(i);
}

// Main kernel: 512 threads = 8 waves, one (b,c) pair per wave.
// Per pair: C(16x80) = A(16 windows x 320) * B(320 x 80 twiddle), bf16 MFMA,
// then shuffle-only epilogue (power + 35-bin normalize), no C LDS buffer.
__global__ __launch_bounds__(512, 4) void st_spec_main(
    const float* __restrict__ x, const int* __restrict__ offs,
    const unsigned short* __restrict__ BpG, float* __restrict__ out)
{
    __shared__ __align__(16) unsigned short Bp[25600];   // 51200 B

    const int tid = threadIdx.x;

    // stage twiddle table global -> LDS (16 B per iteration per thread)
    {
        const u16x8* src = (const u16x8*)BpG;
        u16x8* dst = (u16x8*)Bp;
        #pragma unroll
        for (int i = 0; i < 6; ++i) dst[tid + i * 512] = src[tid + i * 512];
        int i6 = tid + 6 * 512;
        if (i6 < 3200) dst[i6] = src[i6];
    }
    __syncthreads();

    const int wave = tid >> 6;
    const int lane = tid & 63;
    const int bc   = blockIdx.x * 8 + wave;     // 0..4095  (b*32+c)
    const int c16  = lane & 15;                 // A row = window index / C col
    const int kq   = lane >> 4;                 // k-quarter

    const float* xrow = x + (size_t)bc * 9000;
    const int off = offs[bc * 16 + c16];

    // A fragments straight from global (runtime offsets), zero-pad t>=300
    frag_ab a[10];
    #pragma unroll
    for (int kc = 0; kc < 9; ++kc) {           // t <= 295 < 300, safe
        const float* p = xrow + off + kc * 32 + kq * 8;
        f32x4u v0 = *(const f32x4u*)p;
        f32x4u v1 = *(const f32x4u*)(p + 4);
        frag_ab av;
        #pragma unroll
        for (int e = 0; e < 4; ++e) av[e] = (short)f2bf(v0[e]);
        #pragma unroll
        for (int e = 0; e < 4; ++e) av[4 + e] = (short)f2bf(v1[e]);
        a[kc] = av;
    }
    {
        int tb = 288 + kq * 8;                 // last chunk: guard t<300
        frag_ab av;
        #pragma unroll
        for (int e = 0; e < 8; ++e) {
            int t = tb + e;
            av[e] = (short)f2bf((t < 300) ? xrow[off + t] : 0.0f);
        }
        a[9] = av;
    }

    f32x4 acc[5];
    #pragma unroll
    for (int n = 0; n < 5; ++n) acc[n] = (f32x4){0.f, 0.f, 0.f, 0.f};

    #pragma unroll
    for (int kc = 0; kc < 10; ++kc) {
        #pragma unroll
        for (int n = 0; n < 5; ++n) {
            frag_ab b = *(const frag_ab*)&Bp[((kc * 5 + n) * 64 + lane) * 8];
            acc[n] = __builtin_amdgcn_mfma_f32_16x16x32_bf16(a[kc], b, acc[n], 0, 0, 0);
        }
    }

    // Shuffle epilogue. C layout: col = n*16 + (lane&15), row = (lane>>4)*4 + r.
    // re(j) = col j, im(j) = col j+35.  For j = n*16+c:
    //   n=0: im in frag2 lane c+3 (c<13) else frag3 lane c-13
    //   n=1: im in frag3 lane c+3 (c<13) else frag4 lane c-13
    //   n=2 (c<3): im in frag4 lane c+3
    // single source lane works for all: (lane&48) | ((c+3)&15)
    const int src = (lane & 48) | ((c16 + 3) & 15);
    #pragma unroll
    for (int r = 0; r < 4; ++r) {
        float re0 = acc[0][r], re1 = acc[1][r], re2 = acc[2][r];
        float sh2 = __shfl(acc[2][r], src);
        float sh3 = __shfl(acc[3][r], src);
        float sh4 = __shfl(acc[4][r], src);
        float im0 = (c16 < 13) ? sh2 : sh3;
        float im1 = (c16 < 13) ? sh3 : sh4;
        float p0 = re0 * re0 + im0 * im0;
        float p1 = re1 * re1 + im1 * im1;
        float p2 = (c16 < 3) ? (re2 * re2 + sh4 * sh4) : 0.0f;
        float ps = p0 + p1 + p2;
        ps += __shfl_xor(ps, 1);
        ps += __shfl_xor(ps, 2);
        ps += __shfl_xor(ps, 4);
        ps += __shfl_xor(ps, 8);
        float inv = 1.0f / ps;
        int row = kq * 4 + r;
        float* orow = out + ((size_t)bc * 16 + row) * 35;
        orow[c16]      = p0 * inv;
        orow[16 + c16] = p1 * inv;
        if (c16 < 3) orow[32 + c16] = p2 * inv;
    }
}

// ---- fallback (ws too small): self-building variant, known-good from R1 ----
__global__ __launch_bounds__(256) void st_spec_fallback(
    const float* __restrict__ x, const int* __restrict__ offs,
    float* __restrict__ out)
{
    __shared__ __align__(16) short Bp[25600];
    __shared__ float Cbuf[4][16 * 80];
    __shared__ float cT[300], sT[300];

    const int tid = threadIdx.x;
    for (int m = tid; m < 300; m += 256) {
        float s, c;
        sincosf((float)m * 0.020943951023931953f, &s, &c);
        cT[m] = c; sT[m] = s;
    }
    __syncthreads();
    for (int i = tid; i < 25600; i += 256) {
        int e  = i & 7;
        int l  = (i >> 3) & 63;
        int nk = i >> 9;
        int kc = nk / 5;
        int n  = nk - kc * 5;
        int k   = kc * 32 + ((l >> 4) << 3) + e;
        int col = n * 16 + (l & 15);
        float v = 0.0f;
        if (k < 300 && col < 70) {
            int j = (col < 35) ? col : col - 35;
            int m = ((7 + j) * k) % 300;
            v = (col < 35) ? cT[m] : sT[m];
        }
        Bp[i] = (short)f2bf(v);
    }
    __syncthreads();

    const int wave = tid >> 6;
    const int lane = tid & 63;
    const int bc   = blockIdx.x * 4 + wave;
    const int w16  = lane & 15;
    const int kq   = lane >> 4;

    const float* xrow = x + (size_t)bc * 9000;
    const int off = offs[bc * 16 + w16];

    frag_ab a[10];
    #pragma unroll
    for (int kc = 0; kc < 9; ++kc) {
        const float* p = xrow + off + kc * 32 + kq * 8;
        frag_ab av;
        #pragma unroll
        for (int e = 0; e < 8; ++e) av[e] = (short)f2bf(p[e]);
        a[kc] = av;
    }
    {
        int tb = 288 + kq * 8;
        frag_ab av;
        #pragma unroll
        for (int e = 0; e < 8; ++e) {
            int t = tb + e;
            av[e] = (short)f2bf((t < 300) ? xrow[off + t] : 0.0f);
        }
        a[9] = av;
    }

    f32x4 acc[5];
    #pragma unroll
    for (int n = 0; n < 5; ++n) acc[n] = (f32x4){0.f, 0.f, 0.f, 0.f};
    #pragma unroll
    for (int kc = 0; kc < 10; ++kc)
        #pragma unroll
        for (int n = 0; n < 5; ++n) {
            frag_ab b = *(const frag_ab*)&Bp[((kc * 5 + n) * 64 + lane) * 8];
            acc[n] = __builtin_amdgcn_mfma_f32_16x16x32_bf16(a[kc], b, acc[n], 0, 0, 0);
        }

    float* C = Cbuf[wave];
    #pragma unroll
    for (int n = 0; n < 5; ++n)
        #pragma unroll
        for (int r = 0; r < 4; ++r)
            C[(kq * 4 + r) * 80 + n * 16 + w16] = acc[n][r];
    __syncthreads();

    const int w   = lane >> 2;
    const int sub = lane & 3;
    float pv[9];
    float s = 0.f;
    #pragma unroll
    for (int i2 = 0; i2 < 9; ++i2) {
        int j = sub * 9 + i2;
        float p = 0.f;
        if (j < 35) {
            float re = C[w * 80 + j];
            float im = C[w * 80 + 35 + j];
            p = re * re + im * im;
        }
        pv[i2] = p;
        s += p;
    }
    s += __shfl_xor(s, 1);
    s += __shfl_xor(s, 2);
    float inv = 1.0f / s;
    float* orow = out + ((size_t)bc * 16 + w) * 35;
    #pragma unroll
    for (int i2 = 0; i2 < 9; ++i2) {
        int j = sub * 9 + i2;
        if (j < 35) orow[j] = pv[i2] * inv;
    }
}

extern "C" void kernel_launch(void* const* d_in, const int* in_sizes, int n_in,
                              void* d_out, int out_size, void* d_ws, size_t ws_size,
                              hipStream_t stream) {
    const float* x    = (const float*)d_in[0];
    const int*   offs = (const int*)d_in[1];
    float*       out  = (float*)d_out;
    if (ws_size >= 25600 * sizeof(unsigned short)) {
        unsigned short* BpG = (unsigned short*)d_ws;
        hipLaunchKernelGGL(build_twiddle, dim3(100), dim3(256), 0, stream, BpG);
        hipLaunchKernelGGL(st_spec_main, dim3(512), dim3(512), 0, stream,
                           x, offs, BpG, out);
    } else {
        hipLaunchKernelGGL(st_spec_fallback, dim3(1024), dim3(256), 0, stream,
                           x, offs, out);
    }
}

// Round 3
// 23.790 us; speedup vs baseline: 1.8605x; 1.1645x over previous
//
#include <hip/hip_runtime.h>
#include <hip/hip_bf16.h>

using frag_ab = __attribute__((ext_vector_type(8))) short;   // 8 bf16 in 4 VGPRs
using f32x4   = __attribute__((ext_vector_type(4))) float;
typedef float f32x4u __attribute__((ext_vector_type(4), aligned(4)));

// ======== compile-time twiddle table ========
// B(320 x 80): col 0..34 = cos(2*pi*(7+j)*k/300), col 35..69 = sin(...), else 0.
// Packed in MFMA fragment order, one chunk per kc:
//   chunk[kc].v[(n*64 + lane)*8 + e],  k = kc*32 + (lane>>4)*8 + e, col = n*16 + (lane&15)

struct CS { double c[300]; double s[300]; };

constexpr CS make_cs() {
    CS t{};
    const double PI = 3.14159265358979323846;
    for (int m = 0; m < 300; ++m) {
        int q = m / 75, r = m % 75;
        double th = PI * (double)r / 150.0;     // [0, pi/2)
        double x2 = th * th;
        double term = 1.0, cv = 0.0;
        for (int k2 = 0; k2 < 12; ++k2) { cv += term; term *= -x2 / ((2*k2+1)*(2*k2+2)); }
        double sv = 0.0; term = th;
        for (int k2 = 0; k2 < 12; ++k2) { sv += term; term *= -x2 / ((2*k2+2)*(2*k2+3)); }
        double cc = 0.0, ss = 0.0;
        if      (q == 0) { cc =  cv; ss =  sv; }
        else if (q == 1) { cc = -sv; ss =  cv; }
        else if (q == 2) { cc = -cv; ss = -sv; }
        else             { cc =  sv; ss = -cv; }
        t.c[m] = cc; t.s[m] = ss;
    }
    return t;
}
constexpr CS TAB = make_cs();

constexpr unsigned short d2bf(double v) {
    unsigned s = 0; double a = v;
    if (a < 0) { s = 1; a = -a; }
    if (a < 1e-8) return 0;                 // exact zeros of the twiddle grid
    int e = 0;
    while (a >= 2.0) { a *= 0.5; ++e; }
    while (a <  1.0) { a *= 2.0; --e; }
    double m = (a - 1.0) * 128.0;           // 7-bit bf16 mantissa
    int mi = (int)(m + 0.5);
    int ef = 127 + e;
    if (mi == 128) { mi = 0; ++ef; }
    return (unsigned short)((s << 15) | ((unsigned)ef << 7) | (unsigned)mi);
}

struct alignas(16) Chunk { unsigned short v[2560]; };   // [n=5][lane=64][e=8]

constexpr Chunk make_chunk(int kc) {
    Chunk ch{};
    for (int i = 0; i < 2560; ++i) {
        int e = i & 7, l = (i >> 3) & 63, n = i >> 9;
        int k   = kc * 32 + ((l >> 4) << 3) + e;
        int col = n * 16 + (l & 15);
        double v = 0.0;
        if (k < 300 && col < 70) {
            int j = (col < 35) ? col : col - 35;
            int m = ((7 + j) * k) % 300;        // exact integer angle index
            v = (col < 35) ? TAB.c[m] : TAB.s[m];
        }
        ch.v[i] = d2bf(v);
    }
    return ch;
}

__device__ constexpr Chunk BP0 = make_chunk(0);
__device__ constexpr Chunk BP1 = make_chunk(1);
__device__ constexpr Chunk BP2 = make_chunk(2);
__device__ constexpr Chunk BP3 = make_chunk(3);
__device__ constexpr Chunk BP4 = make_chunk(4);
__device__ constexpr Chunk BP5 = make_chunk(5);
__device__ constexpr Chunk BP6 = make_chunk(6);
__device__ constexpr Chunk BP7 = make_chunk(7);
__device__ constexpr Chunk BP8 = make_chunk(8);
__device__ constexpr Chunk BP9 = make_chunk(9);

__device__ __forceinline__ const unsigned short* bp_ptr(int kc) {
    switch (kc) {
        case 0: return BP0.v; case 1: return BP1.v; case 2: return BP2.v;
        case 3: return BP3.v; case 4: return BP4.v; case 5: return BP5.v;
        case 6: return BP6.v; case 7: return BP7.v; case 8: return BP8.v;
        default: return BP9.v;
    }
}

__device__ __forceinline__ unsigned short f2bf(float f) {
    unsigned u = __float_as_uint(f);
    u += 0x7fffu + ((u >> 16) & 1u);          // RNE
    return (unsigned short)(u >> 16);
}

// One wave per (b,c) pair: C(16x80) = A(16 windows x 320) * B(320 x 80), bf16
// MFMA, shuffle-only epilogue. No LDS, no barriers; B read from L2-resident
// compile-time table.
__global__ __launch_bounds__(256) void st_spec_main(
    const float* __restrict__ x, const int* __restrict__ offs,
    float* __restrict__ out)
{
    const int tid  = threadIdx.x;
    const int wave = tid >> 6;
    const int lane = tid & 63;
    const int bc   = blockIdx.x * 4 + wave;     // 0..4095 (b*32+c)
    const int c16  = lane & 15;                 // A row = window index / C col
    const int kq   = lane >> 4;                 // k-quarter

    const float* xrow = x + (size_t)bc * 9000;
    const int off = offs[bc * 16 + c16];

    // A fragments straight from global (runtime offsets), zero-pad t>=300
    frag_ab a[10];
    #pragma unroll
    for (int kc = 0; kc < 9; ++kc) {           // t <= 295 < 300, safe
        const float* p = xrow + off + kc * 32 + kq * 8;
        f32x4u v0 = *(const f32x4u*)p;
        f32x4u v1 = *(const f32x4u*)(p + 4);
        frag_ab av;
        #pragma unroll
        for (int e = 0; e < 4; ++e) av[e] = (short)f2bf(v0[e]);
        #pragma unroll
        for (int e = 0; e < 4; ++e) av[4 + e] = (short)f2bf(v1[e]);
        a[kc] = av;
    }
    {
        int tb = 288 + kq * 8;                 // last chunk: guard t<300
        frag_ab av;
        #pragma unroll
        for (int e = 0; e < 8; ++e) {
            int t = tb + e;
            av[e] = (short)f2bf((t < 300) ? xrow[off + t] : 0.0f);
        }
        a[9] = av;
    }

    f32x4 acc[5];
    #pragma unroll
    for (int n = 0; n < 5; ++n) acc[n] = (f32x4){0.f, 0.f, 0.f, 0.f};

    #pragma unroll
    for (int kc = 0; kc < 10; ++kc) {
        const unsigned short* bp = bp_ptr(kc);
        #pragma unroll
        for (int n = 0; n < 5; ++n) {
            frag_ab b = *(const frag_ab*)&bp[(n * 64 + lane) * 8];
            acc[n] = __builtin_amdgcn_mfma_f32_16x16x32_bf16(a[kc], b, acc[n], 0, 0, 0);
        }
    }

    // Shuffle epilogue. C layout: col = n*16 + (lane&15), row = (lane>>4)*4 + r.
    // re(j) = col j, im(j) = col j+35; single source lane (lane&48)|((c+3)&15).
    const int src = (lane & 48) | ((c16 + 3) & 15);
    #pragma unroll
    for (int r = 0; r < 4; ++r) {
        float re0 = acc[0][r], re1 = acc[1][r], re2 = acc[2][r];
        float sh2 = __shfl(acc[2][r], src);
        float sh3 = __shfl(acc[3][r], src);
        float sh4 = __shfl(acc[4][r], src);
        float im0 = (c16 < 13) ? sh2 : sh3;
        float im1 = (c16 < 13) ? sh3 : sh4;
        float p0 = re0 * re0 + im0 * im0;
        float p1 = re1 * re1 + im1 * im1;
        float p2 = (c16 < 3) ? (re2 * re2 + sh4 * sh4) : 0.0f;
        float ps = p0 + p1 + p2;
        ps += __shfl_xor(ps, 1);
        ps += __shfl_xor(ps, 2);
        ps += __shfl_xor(ps, 4);
        ps += __shfl_xor(ps, 8);
        float inv = 1.0f / ps;
        int row = kq * 4 + r;
        float* orow = out + ((size_t)bc * 16 + row) * 35;
        orow[c16]      = p0 * inv;
        orow[16 + c16] = p1 * inv;
        if (c16 < 3) orow[32 + c16] = p2 * inv;
    }
}

extern "C" void kernel_launch(void* const* d_in, const int* in_sizes, int n_in,
                              void* d_out, int out_size, void* d_ws, size_t ws_size,
                              hipStream_t stream) {
    const float* x    = (const float*)d_in[0];
    const int*   offs = (const int*)d_in[1];
    float*       out  = (float*)d_out;
    hipLaunchKernelGGL(st_spec_main, dim3(1024), dim3(256), 0, stream,
                       x, offs, out);
}

// Round 4
// 20.425 us; speedup vs baseline: 2.1671x; 1.1648x over previous
//
#include <hip/hip_runtime.h>
#include <hip/hip_bf16.h>

using frag_ab = __attribute__((ext_vector_type(8))) short;   // 8 bf16 in 4 VGPRs
using f32x4   = __attribute__((ext_vector_type(4))) float;
using i32x4   = __attribute__((ext_vector_type(4))) int;
typedef float f32x4u __attribute__((ext_vector_type(4), aligned(4)));
using u16x8   = __attribute__((ext_vector_type(8))) unsigned short;  // 16 B

// ======== compile-time twiddle table ========
// B(320 x 80): col 0..34 = cos(2*pi*(7+j)*k/300), col 35..69 = sin(...), else 0.
// Packed in MFMA fragment order, one chunk per kc:
//   chunk[kc].v[(n*64 + lane)*8 + e],  k = kc*32 + (lane>>4)*8 + e, col = n*16 + (lane&15)

struct CS { double c[300]; double s[300]; };

constexpr CS make_cs() {
    CS t{};
    const double PI = 3.14159265358979323846;
    for (int m = 0; m < 300; ++m) {
        int q = m / 75, r = m % 75;
        double th = PI * (double)r / 150.0;     // [0, pi/2)
        double x2 = th * th;
        double term = 1.0, cv = 0.0;
        for (int k2 = 0; k2 < 12; ++k2) { cv += term; term *= -x2 / ((2*k2+1)*(2*k2+2)); }
        double sv = 0.0; term = th;
        for (int k2 = 0; k2 < 12; ++k2) { sv += term; term *= -x2 / ((2*k2+2)*(2*k2+3)); }
        double cc = 0.0, ss = 0.0;
        if      (q == 0) { cc =  cv; ss =  sv; }
        else if (q == 1) { cc = -sv; ss =  cv; }
        else if (q == 2) { cc = -cv; ss = -sv; }
        else             { cc =  sv; ss = -cv; }
        t.c[m] = cc; t.s[m] = ss;
    }
    return t;
}
constexpr CS TAB = make_cs();

constexpr unsigned short d2bf(double v) {
    unsigned s = 0; double a = v;
    if (a < 0) { s = 1; a = -a; }
    if (a < 1e-8) return 0;                 // exact zeros of the twiddle grid
    int e = 0;
    while (a >= 2.0) { a *= 0.5; ++e; }
    while (a <  1.0) { a *= 2.0; --e; }
    double m = (a - 1.0) * 128.0;           // 7-bit bf16 mantissa
    int mi = (int)(m + 0.5);
    int ef = 127 + e;
    if (mi == 128) { mi = 0; ++ef; }
    return (unsigned short)((s << 15) | ((unsigned)ef << 7) | (unsigned)mi);
}

struct alignas(16) Chunk { unsigned short v[2560]; };   // [n=5][lane=64][e=8]

constexpr Chunk make_chunk(int kc) {
    Chunk ch{};
    for (int i = 0; i < 2560; ++i) {
        int e = i & 7, l = (i >> 3) & 63, n = i >> 9;
        int k   = kc * 32 + ((l >> 4) << 3) + e;
        int col = n * 16 + (l & 15);
        double v = 0.0;
        if (k < 300 && col < 70) {
            int j = (col < 35) ? col : col - 35;
            int m = ((7 + j) * k) % 300;        // exact integer angle index
            v = (col < 35) ? TAB.c[m] : TAB.s[m];
        }
        ch.v[i] = d2bf(v);
    }
    return ch;
}

__device__ constexpr Chunk BPALL[10] = {
    make_chunk(0), make_chunk(1), make_chunk(2), make_chunk(3), make_chunk(4),
    make_chunk(5), make_chunk(6), make_chunk(7), make_chunk(8), make_chunk(9)
};

// 2 f32 -> packed 2x bf16 (low = lo, high = hi), single HW instruction
__device__ __forceinline__ unsigned cvtpk(float lo, float hi) {
    unsigned r;
    asm("v_cvt_pk_bf16_f32 %0, %1, %2" : "=v"(r) : "v"(lo), "v"(hi));
    return r;
}

// 512 threads = 8 waves, one (b,c) pair per wave.
// C(16x80) = A(16 windows x 320) * B(320 x 80), bf16 MFMA.
// B staged once to LDS (off the L1 path); A gathered straight from global;
// shuffle-only epilogue.
__global__ __launch_bounds__(512) void st_spec_main(
    const float* __restrict__ x, const int* __restrict__ offs,
    float* __restrict__ out)
{
    __shared__ __align__(16) unsigned short Bp[25600];   // 51200 B

    const int tid = threadIdx.x;

    // stage twiddle table: constexpr global -> LDS, 16 B per thread-iter
    {
        const u16x8* src = (const u16x8*)&BPALL[0];
        u16x8* dst = (u16x8*)Bp;
        #pragma unroll
        for (int i = 0; i < 6; ++i) dst[tid + i * 512] = src[tid + i * 512];
        int i6 = tid + 6 * 512;
        if (i6 < 3200) dst[i6] = src[i6];
    }

    const int wave = tid >> 6;
    const int lane = tid & 63;
    const int bc   = blockIdx.x * 8 + wave;     // 0..4095 (b*32+c)
    const int c16  = lane & 15;                 // A row = window index / C col
    const int kq   = lane >> 4;                 // k-quarter

    const float* xrow = x + (size_t)bc * 9000;
    const int off = offs[bc * 16 + c16];

    // A fragments straight from global (runtime offsets), zero-pad t>=300
    frag_ab a[10];
    #pragma unroll
    for (int kc = 0; kc < 9; ++kc) {           // t <= 295 < 300, safe
        const float* p = xrow + off + kc * 32 + kq * 8;
        f32x4u v0 = *(const f32x4u*)p;
        f32x4u v1 = *(const f32x4u*)(p + 4);
        i32x4 w;
        w[0] = cvtpk(v0[0], v0[1]);
        w[1] = cvtpk(v0[2], v0[3]);
        w[2] = cvtpk(v1[0], v1[1]);
        w[3] = cvtpk(v1[2], v1[3]);
        a[kc] = __builtin_bit_cast(frag_ab, w);
    }
    {
        int tb = 288 + kq * 8;                 // last chunk: guard t<300
        float v[8];
        #pragma unroll
        for (int e = 0; e < 8; ++e) {
            int t = tb + e;
            v[e] = (t < 300) ? xrow[off + t] : 0.0f;
        }
        i32x4 w;
        w[0] = cvtpk(v[0], v[1]);
        w[1] = cvtpk(v[2], v[3]);
        w[2] = cvtpk(v[4], v[5]);
        w[3] = cvtpk(v[6], v[7]);
        a[9] = __builtin_bit_cast(frag_ab, w);
    }

    __syncthreads();                            // Bp ready

    f32x4 acc[5];
    #pragma unroll
    for (int n = 0; n < 5; ++n) acc[n] = (f32x4){0.f, 0.f, 0.f, 0.f};

    #pragma unroll
    for (int kc = 0; kc < 10; ++kc) {
        #pragma unroll
        for (int n = 0; n < 5; ++n) {
            frag_ab b = *(const frag_ab*)&Bp[((kc * 5 + n) * 64 + lane) * 8];
            acc[n] = __builtin_amdgcn_mfma_f32_16x16x32_bf16(a[kc], b, acc[n], 0, 0, 0);
        }
    }

    // Shuffle epilogue. C layout: col = n*16 + (lane&15), row = (lane>>4)*4 + r.
    // re(j) = col j, im(j) = col j+35; single source lane (lane&48)|((c+3)&15).
    const int src = (lane & 48) | ((c16 + 3) & 15);
    #pragma unroll
    for (int r = 0; r < 4; ++r) {
        float re0 = acc[0][r], re1 = acc[1][r], re2 = acc[2][r];
        float sh2 = __shfl(acc[2][r], src);
        float sh3 = __shfl(acc[3][r], src);
        float sh4 = __shfl(acc[4][r], src);
        float im0 = (c16 < 13) ? sh2 : sh3;
        float im1 = (c16 < 13) ? sh3 : sh4;
        float p0 = re0 * re0 + im0 * im0;
        float p1 = re1 * re1 + im1 * im1;
        float p2 = (c16 < 3) ? (re2 * re2 + sh4 * sh4) : 0.0f;
        float ps = p0 + p1 + p2;
        ps += __shfl_xor(ps, 1);
        ps += __shfl_xor(ps, 2);
        ps += __shfl_xor(ps, 4);
        ps += __shfl_xor(ps, 8);
        float inv = 1.0f / ps;
        int row = kq * 4 + r;
        float* orow = out + ((size_t)bc * 16 + row) * 35;
        orow[c16]      = p0 * inv;
        orow[16 + c16] = p1 * inv;
        if (c16 < 3) orow[32 + c16] = p2 * inv;
    }
}

extern "C" void kernel_launch(void* const* d_in, const int* in_sizes, int n_in,
                              void* d_out, int out_size, void* d_ws, size_t ws_size,
                              hipStream_t stream) {
    const float* x    = (const float*)d_in[0];
    const int*   offs = (const int*)d_in[1];
    float*       out  = (float*)d_out;
    // 4096 (b,c) pairs, 8 per block
    hipLaunchKernelGGL(st_spec_main, dim3(512), dim3(512), 0, stream,
                       x, offs, out);
}